// Round 1
// baseline (189.321 us; speedup 1.0000x reference)
//
#include <hip/hip_runtime.h>

// out[b,l,k] = -sum_ij Gamma[b,l,k,i,j] * dz[b,l,i] * dz[b,l,j]
// D = 32. One block per (b,l). 256 threads = 4 waves; wave w handles k in [8w, 8w+8).
// Per k-slab (32x32 f32 = 4 KB): 64 lanes x 4 float4 iterations, fully coalesced.

#define D 32

__global__ __launch_bounds__(256) void geodesic_accel_kernel(
    const float* __restrict__ dz,
    const float* __restrict__ Gamma,
    float* __restrict__ out)
{
    const int bl = blockIdx.x;
    const float* __restrict__ G = Gamma + (size_t)bl * (D * D * D);
    const float* __restrict__ z = dz + (size_t)bl * D;
    float* __restrict__ o = out + (size_t)bl * D;

    const int tid  = threadIdx.x;
    const int wave = tid >> 6;
    const int lane = tid & 63;

    // Per-lane fixed j block: j0..j0+3
    const int j0 = (lane & 7) * 4;
    const float4 zj = *reinterpret_cast<const float4*>(z + j0);

    // i for iteration m: i = m*8 + (lane>>3)
    const int ibase = lane >> 3;
    float4 w4[4];
#pragma unroll
    for (int m = 0; m < 4; ++m) {
        const float zi = z[m * 8 + ibase];
        w4[m] = make_float4(zi * zj.x, zi * zj.y, zi * zj.z, zi * zj.w);
    }

    // 8 k-slabs per wave
#pragma unroll
    for (int s = 0; s < 8; ++s) {
        const int k = wave * 8 + s;
        const float4* __restrict__ Gk =
            reinterpret_cast<const float4*>(G + k * (D * D));
        float acc = 0.f;
#pragma unroll
        for (int m = 0; m < 4; ++m) {
            const float4 g = Gk[m * 64 + lane];
            acc += g.x * w4[m].x + g.y * w4[m].y + g.z * w4[m].z + g.w * w4[m].w;
        }
        // wave-wide butterfly reduce (64 lanes)
#pragma unroll
        for (int off = 32; off > 0; off >>= 1) {
            acc += __shfl_xor(acc, off);
        }
        if (lane == 0) {
            o[k] = -acc;
        }
    }
}

extern "C" void kernel_launch(void* const* d_in, const int* in_sizes, int n_in,
                              void* d_out, int out_size, void* d_ws, size_t ws_size,
                              hipStream_t stream)
{
    const float* dz    = (const float*)d_in[0];
    const float* Gamma = (const float*)d_in[1];
    float* out         = (float*)d_out;

    const int n_bl = in_sizes[0] / D;  // B*L = 8192
    geodesic_accel_kernel<<<n_bl, 256, 0, stream>>>(dz, Gamma, out);
}

// Round 3
// 167.779 us; speedup vs baseline: 1.1284x; 1.1284x over previous
//
#include <hip/hip_runtime.h>

// out[b,l,k] = -sum_ij Gamma[b,l,k,i,j] * dz[b,l,i] * dz[b,l,j]
// D = 32. One block per (b,l). 256 threads = 4 waves; wave w owns k in [8w, 8w+8).
// m-outer / slab-inner: 8 independent load->FMA streams, no cross-lane ops in
// the hot loop; merged 10-shuffle reduce tree at the end. Nontemporal Gamma loads.

#define D 32

typedef float f32x4 __attribute__((ext_vector_type(4)));

__device__ __forceinline__ float red_step(float a, float b, int off, int lane) {
    // One shuffle folds two accumulators: returns pair-sum of `a` on lanes with
    // (lane&off)==0 and pair-sum of `b` on lanes with (lane&off)!=0.
    float t = (lane & off) ? a : b;
    t = __shfl_xor(t, off);
    return (lane & off) ? (b + t) : (a + t);
}

__global__ __launch_bounds__(256) void geodesic_accel_kernel(
    const float* __restrict__ dz,
    const float* __restrict__ Gamma,
    float* __restrict__ out)
{
    const int bl = blockIdx.x;
    const float* __restrict__ G = Gamma + (size_t)bl * (D * D * D);
    const float* __restrict__ z = dz + (size_t)bl * D;
    float* __restrict__ o = out + (size_t)bl * D;

    const int tid  = threadIdx.x;
    const int wave = tid >> 6;
    const int lane = tid & 63;

    // Per-lane fixed j block: j0..j0+3
    const int j0 = (lane & 7) * 4;
    const f32x4 zj = *reinterpret_cast<const f32x4*>(z + j0);

    // i for iteration m: i = m*8 + (lane>>3)
    const int ibase = lane >> 3;
    f32x4 w4[4];
#pragma unroll
    for (int m = 0; m < 4; ++m) {
        const float zi = z[m * 8 + ibase];
        w4[m] = zi * zj;
    }

    // Base f32x4 pointer for this wave's 8 k-slabs (each slab = 32x32 f32 = 256 f32x4)
    const f32x4* __restrict__ Gw =
        reinterpret_cast<const f32x4*>(G + (wave * 8) * (D * D));

    float acc[8] = {0.f, 0.f, 0.f, 0.f, 0.f, 0.f, 0.f, 0.f};

#pragma unroll
    for (int m = 0; m < 4; ++m) {
        const f32x4 w = w4[m];
#pragma unroll
        for (int s = 0; s < 8; ++s) {
            const f32x4 g = __builtin_nontemporal_load(Gw + s * 256 + m * 64 + lane);
            acc[s] = fmaf(g.x, w.x,
                     fmaf(g.y, w.y,
                     fmaf(g.z, w.z,
                     fmaf(g.w, w.w, acc[s]))));
        }
    }

    // Merged reduce: 3 multiplexing steps (7 shuffles) collapse 8 accs -> 1 reg
    // holding acc[lane&7] summed over each 8-lane group, then 3 plain butterfly
    // steps finish the 64-lane sum.
    float r0 = red_step(acc[0], acc[1], 1, lane);
    float r1 = red_step(acc[2], acc[3], 1, lane);
    float r2 = red_step(acc[4], acc[5], 1, lane);
    float r3 = red_step(acc[6], acc[7], 1, lane);
    float s0 = red_step(r0, r1, 2, lane);
    float s1 = red_step(r2, r3, 2, lane);
    float t0 = red_step(s0, s1, 4, lane);
    t0 += __shfl_xor(t0, 8);
    t0 += __shfl_xor(t0, 16);
    t0 += __shfl_xor(t0, 32);

    if (lane < 8) {
        o[wave * 8 + lane] = -t0;
    }
}

extern "C" void kernel_launch(void* const* d_in, const int* in_sizes, int n_in,
                              void* d_out, int out_size, void* d_ws, size_t ws_size,
                              hipStream_t stream)
{
    const float* dz    = (const float*)d_in[0];
    const float* Gamma = (const float*)d_in[1];
    float* out         = (float*)d_out;

    const int n_bl = in_sizes[0] / D;  // B*L = 8192
    geodesic_accel_kernel<<<n_bl, 256, 0, stream>>>(dz, Gamma, out);
}